// Round 1
// baseline (456.987 us; speedup 1.0000x reference)
//
#include <hip/hip_runtime.h>
#include <math.h>

// Problem constants (fixed by setup_inputs)
constexpr int KV_LEN    = 4096;
constexpr int PAGE_SZ   = 16;
constexpr int SHIFT     = 16;
constexpr int BSZ       = 4;
constexpr int SEQ_LEN   = 512;
constexpr int HEADS     = 16;
constexpr int HEAD_DIM  = 128;
constexpr int PAGES     = BSZ * KV_LEN / PAGE_SZ;  // 1024
constexpr int PPS       = PAGES / BSZ;             // 256 pages per sequence
constexpr int KEEP      = KV_LEN - SHIFT;          // 4080
constexpr int CUT       = KEEP - SEQ_LEN;          // 3568: j<CUT -> cache[j+528]
constexpr int PAGE_STR  = 2 * PAGE_SZ * HEADS * HEAD_DIM;  // 65536 floats
constexpr int C_STR     = PAGE_SZ * HEADS * HEAD_DIM;      // 32768
constexpr int S_STR     = HEADS * HEAD_DIM;                // 2048

// inv[page] = position of `page` in kv_page_indices, or -1 if absent.
// PAGES==1024 fits one block; __syncthreads orders init vs scatter.
__global__ void build_inv(const int* __restrict__ idx, int* __restrict__ inv, int n) {
    int t = threadIdx.x;
    if (t < n) inv[t] = -1;
    __syncthreads();
    if (t < n) inv[idx[t]] = t;
}

// One block per (page, c, s) slab: 16 heads x 128 dims = 2048 floats.
// 256 threads, each handles the RoPE pair (d0..d0+3, d0+64..d0+67) as 2x float4.
__global__ __launch_bounds__(256) void kv_shift_rope(
    const float* __restrict__ kin, const float* __restrict__ vin,
    const float* __restrict__ dc,  const int*  __restrict__ pidx,
    const int*  __restrict__ inv,  float* __restrict__ out)
{
    int blk = blockIdx.x;          // PAGES*2*PAGE_SZ
    int p   = blk >> 5;
    int rem = blk & 31;
    int c   = rem >> 4;            // 0=k, 1=v
    int s   = rem & 15;

    int tid = threadIdx.x;
    int h   = tid >> 4;
    int d0  = (tid & 15) << 2;     // 0..60 step 4

    float* op   = out + (size_t)p * PAGE_STR + c * C_STR + s * S_STR;
    int    off1 = h * HEAD_DIM + d0;
    int    off2 = off1 + 64;

    int pos = inv[p];              // block-uniform
    const float* sp;
    int j = 0;
    if (pos < 0) {
        // page not updated: passthrough copy
        sp = dc + (size_t)p * PAGE_STR + c * C_STR + s * S_STR;
    } else {
        int b  = pos >> 8;         // /PPS (256)
        int pp = pos & (PPS - 1);
        j = pp * PAGE_SZ + s;      // absolute sequence position, 0..4095
        if (j >= CUT && j < KEEP) {
            // sourced from the new k/v tensors
            const float* base = (c == 0) ? kin : vin;
            sp = base + (size_t)(b * SEQ_LEN + (j - CUT)) * S_STR;
        } else {
            // sourced from the old cache (shifted window or retained tail)
            int t2 = (j < CUT) ? (j + SHIFT + SEQ_LEN) : j;
            int q  = t2 >> 4;
            int ss = t2 & 15;
            int srcpage = pidx[b * PPS + q];
            sp = dc + (size_t)srcpage * PAGE_STR + c * C_STR + ss * S_STR;
        }
    }

    float4 x1 = *(const float4*)(sp + off1);
    float4 x2 = *(const float4*)(sp + off2);

    if (pos >= 0 && c == 0) {
        // RoPE (neox rotate-half) at position j, fp32
        const float neg_log2_theta_over_half = -0.20762050593046939f; // -log2(10000)/64
        float fj = (float)j;
        float o1[4], o2[4];
        float a1[4] = {x1.x, x1.y, x1.z, x1.w};
        float a2[4] = {x2.x, x2.y, x2.z, x2.w};
        #pragma unroll
        for (int i = 0; i < 4; i++) {
            float invf = exp2f((float)(d0 + i) * neg_log2_theta_over_half);
            float ang  = fj * invf;
            float sn, cs;
            sincosf(ang, &sn, &cs);
            o1[i] = a1[i] * cs - a2[i] * sn;
            o2[i] = a1[i] * sn + a2[i] * cs;
        }
        *(float4*)(op + off1) = make_float4(o1[0], o1[1], o1[2], o1[3]);
        *(float4*)(op + off2) = make_float4(o2[0], o2[1], o2[2], o2[3]);
    } else {
        *(float4*)(op + off1) = x1;
        *(float4*)(op + off2) = x2;
    }
}

extern "C" void kernel_launch(void* const* d_in, const int* in_sizes, int n_in,
                              void* d_out, int out_size, void* d_ws, size_t ws_size,
                              hipStream_t stream) {
    const float* kin  = (const float*)d_in[0];
    const float* vin  = (const float*)d_in[1];
    const float* dc   = (const float*)d_in[2];
    const int*   pidx = (const int*)d_in[3];
    int pages = in_sizes[3];           // 1024

    int* inv = (int*)d_ws;             // 4 KB scratch
    build_inv<<<1, pages, 0, stream>>>(pidx, inv, pages);

    int grid = PAGES * 2 * PAGE_SZ;    // 32768 blocks
    kv_shift_rope<<<grid, 256, 0, stream>>>(kin, vin, dc, pidx, inv, (float*)d_out);
}